// Round 3
// baseline (1146.908 us; speedup 1.0000x reference)
//
#include <hip/hip_runtime.h>
#include <hip/hip_bf16.h>

// Round 10 == Round 9 resubmitted (round 9 bench died to container/infra
// failure: no compile error, no test failure, degraded push timings).
// r9 changes vs r8: (1) all 24 fragments read in ph1 of each K-tile ->
// phases 2-5 stage-only -> both K-tile boundaries use counted vmcnt(6)
// (3 half-tiles in flight, m201 depth); (2) XCD-aware bijective block
// swizzle (T1); (3) sched_barrier(0) fences pin phase contents.
// Accumulation order unchanged -> numerics identical to r8.
// f32 in/out per reference; bf16 MFMA internally. B=8, N=2048, DA=768, DB=1024.

#define AS1 __attribute__((address_space(1)))
#define AS3 __attribute__((address_space(3)))

typedef __attribute__((ext_vector_type(8))) short bf16x8;
typedef __attribute__((ext_vector_type(4))) float f32x4;

using bf = __hip_bfloat16;

// ---------------- unified 256x256 8-phase GEMM ----------------
// C = alpha * A[M,K] @ BT[Nc,K]^T.
// nseg==1: (+bias)(+resid32/resid16) -> C16 and/or C32, ldc=Nc, tstore bit0.
// nseg>1 : 1024-col segments -> {C16,C16b,C16c} w/ biases {bias,biasB,biasC};
//          tstore bit s stores segment s transposed per 2048-row batch.
// Constraints: M%256==0, Nc%256==0, K%128==0, gx*gy%8==0 (all sites satisfy).
__global__ __launch_bounds__(512, 1) void gemm256(
    const bf* __restrict__ A, const bf* __restrict__ BT,
    const float* __restrict__ bias, const float* __restrict__ biasB,
    const float* __restrict__ biasC,
    const float* __restrict__ resid32, const bf* __restrict__ resid16,
    bf* __restrict__ C16, bf* __restrict__ C16b, bf* __restrict__ C16c,
    float* __restrict__ C32,
    int M, int Nc, int K, float alpha,
    long sA, long sB, long sC, int tstore, int nseg)
{
    // [slot:2][region:4][row:128][col:64] bf16 = 128 KiB.
    // region 0 = A rows [0,128), 1 = B rows [0,128), 2 = A rows [128,256),
    // region 3 = B rows [128,256). slot = K-tile & 1.
    __shared__ __align__(16) char lds[131072];

    const int tid  = threadIdx.x;
    const int wave = tid >> 6;        // 0..7
    const int lane = tid & 63;
    const int wm = wave >> 2;         // 0..1 : M half (128 rows)
    const int wn = wave & 3;          // 0..3 : N quarter (64 cols)

    // XCD-aware bijective swizzle (T1, m157 form; valid since gx*gy%8==0):
    // hardware dispatch round-robins XCD by linear id & 7; remap so XCD k
    // owns a contiguous row-major band of tiles.
    const int gx = gridDim.x, gy = gridDim.y;
    int wg = blockIdx.y * gx + blockIdx.x;
    const int nwg = gx * gy;
    if (!(nwg & 7)) wg = (wg & 7) * (nwg >> 3) + (wg >> 3);
    const int m0 = (wg / gx) * 256;
    const int n0 = (wg % gx) * 256;

    const long zC = (long)blockIdx.z * sC;
    A  += (long)blockIdx.z * sA;
    BT += (long)blockIdx.z * sB;

    const int fl = lane & 15, qd = lane >> 4;
    const int sr = lane >> 3;             // staging sub-row within 8-row group
    const int scn = (lane & 7) ^ sr;      // pre-swizzled global chunk
    const long ldb = (long)K * 2;

    // Staging: each wave covers region-rows [wave*16, wave*16+16), 2 issues
    // of 8 rows. LDS dest linear (global_load_lds constraint); source chunk
    // pre-swizzled so LDS slot s of row R holds global chunk s ^ (R&7).
    const char* gA = (const char*)A  + (long)(m0 + wave * 16 + sr) * ldb + scn * 16;
    const char* gB = (const char*)BT + (long)(n0 + wave * 16 + sr) * ldb + scn * 16;

    auto stage_ht = [&](int s) {   // s = half-tile position: tile s>>2, region s&3
        const int t = s >> 2, r = s & 3;
        const char* g = ((r & 1) ? gB : gA) + (long)((r >> 1) * 128) * ldb + (long)t * 128;
        char* l = lds + ((t & 1) * 65536) + r * 16384 + wave * 2048;
        __builtin_amdgcn_global_load_lds((const AS1 void*)g,               (AS3 void*)l,          16, 0, 0);
        __builtin_amdgcn_global_load_lds((const AS1 void*)(g + 8 * ldb),   (AS3 void*)(l + 1024), 16, 0, 0);
    };

    // Fragment reads: row R in region, k-chunk c=(h<<2)|qd at slot c^(R&7);
    // R&7 == fl&7 for all fragment rows.
    const int xo = fl & 7;
    const int so0 = ((0 | qd) ^ xo) * 16;   // k-half 0 byte slot
    const int so1 = ((4 | qd) ^ xo) * 16;   // k-half 1 byte slot
    const char* Abase = lds + (wm ? 2 : 0) * 16384 + fl * 128;
    const char* Bbase = lds + ((wn >> 1) ? 3 : 1) * 16384 + (wn & 1) * 64 * 128 + fl * 128;

    f32x4 acc[8][4];
#pragma unroll
    for (int i = 0; i < 8; ++i)
#pragma unroll
        for (int j = 0; j < 4; ++j)
            acc[i][j] = (f32x4){0.f, 0.f, 0.f, 0.f};

    bf16x8 afr[2][4][2];   // [mq][Mfrag][khalf]
    bf16x8 bfr[2][2][2];   // [nq][Nfrag][khalf]

#define READ_A(mq, SL) { const char* pA_ = Abase + (SL) * 65536 + (mq) * 8192; \
    _Pragma("unroll") for (int f_ = 0; f_ < 4; ++f_) { \
        afr[mq][f_][0] = *(const bf16x8*)(pA_ + f_ * 2048 + so0); \
        afr[mq][f_][1] = *(const bf16x8*)(pA_ + f_ * 2048 + so1); } }

#define READ_B(nq, SL) { const char* pB_ = Bbase + (SL) * 65536 + (nq) * 4096; \
    _Pragma("unroll") for (int g_ = 0; g_ < 2; ++g_) { \
        bfr[nq][g_][0] = *(const bf16x8*)(pB_ + g_ * 2048 + so0); \
        bfr[nq][g_][1] = *(const bf16x8*)(pB_ + g_ * 2048 + so1); } }

#define MFMA_Q(mq, nq) { \
    __builtin_amdgcn_s_setprio(1); \
    _Pragma("unroll") for (int f_ = 0; f_ < 4; ++f_) \
    _Pragma("unroll") for (int g_ = 0; g_ < 2; ++g_) { \
        acc[(mq)*4+f_][(nq)*2+g_] = __builtin_amdgcn_mfma_f32_16x16x32_bf16( \
            afr[mq][f_][0], bfr[nq][g_][0], acc[(mq)*4+f_][(nq)*2+g_], 0, 0, 0); \
        acc[(mq)*4+f_][(nq)*2+g_] = __builtin_amdgcn_mfma_f32_16x16x32_bf16( \
            afr[mq][f_][1], bfr[nq][g_][1], acc[(mq)*4+f_][(nq)*2+g_], 0, 0, 0); } \
    __builtin_amdgcn_s_setprio(0); }

#define SB()  __builtin_amdgcn_sched_barrier(0)
#define BARS() { SB(); __builtin_amdgcn_s_barrier(); SB(); }
#define VMCNT6() asm volatile("s_waitcnt vmcnt(6)" ::: "memory")
#define VMCNT0() asm volatile("s_waitcnt vmcnt(0)" ::: "memory")
#define STG(S) { if ((S) < nht) stage_ht(S); }

    const int NT    = K >> 6;     // K-tiles (even at all call sites)
    const int niter = NT >> 1;
    const int nht   = NT << 2;

    // Prologue: 7 half-tiles (tile0 all + tile1 r0..r2); vmcnt(6) -> tile0 landed.
#pragma unroll
    for (int s = 0; s < 7; ++s) stage_ht(s);
    VMCNT6();
    BARS();

    for (int I = 0; I < niter; ++I) {
        const int s0 = 8 * I + 7;           // rolling stage cursor
        const bool last = (I == niter - 1);
        // ---- K-tile 2I (slot 0): all frags read in ph1 ----
        READ_A(0, 0); READ_B(0, 0); READ_A(1, 0); READ_B(1, 0);
        STG(s0 + 0); BARS(); MFMA_Q(0, 0); BARS();
        STG(s0 + 1); BARS(); MFMA_Q(1, 1); BARS();
        STG(s0 + 2); BARS(); MFMA_Q(0, 1); BARS();
        STG(s0 + 3); BARS(); MFMA_Q(1, 0);
        // boundary: tile 2I+1 must be landed (oldest loads); 6 newest may fly
        if (last) { VMCNT0(); } else { VMCNT6(); }
        BARS();
        // ---- K-tile 2I+1 (slot 1): all frags read in ph5 ----
        READ_A(0, 1); READ_B(0, 1); READ_A(1, 1); READ_B(1, 1);
        STG(s0 + 4); BARS(); MFMA_Q(0, 0); BARS();
        STG(s0 + 5); BARS(); MFMA_Q(1, 1); BARS();
        STG(s0 + 6); BARS(); MFMA_Q(0, 1); BARS();
        STG(s0 + 7); BARS(); MFMA_Q(1, 0);
        if (!last) { VMCNT6(); }
        BARS();
    }

    // Epilogue: C/D layout col = lane&15, row = qd*4 + r (verified m89/m91).
    if (nseg == 1) {
        const long ldc = Nc;
#pragma unroll
        for (int i = 0; i < 8; ++i) {
#pragma unroll
            for (int j = 0; j < 4; ++j) {
#pragma unroll
                for (int r = 0; r < 4; ++r) {
                    const int row = m0 + wm * 128 + i * 16 + qd * 4 + r;
                    const int col = n0 + wn * 64 + j * 16 + fl;
                    float v = acc[i][j][r] * alpha;
                    if (bias) v += bias[col];
                    if (tstore & 1) {
                        const long idx = (long)(row >> 11) * ((long)Nc * 2048)
                                       + (long)col * 2048 + (row & 2047);
                        C16[idx] = __float2bfloat16(v);
                    } else {
                        const long idx = zC + (long)row * ldc + col;
                        if (resid32) v += resid32[idx];
                        if (resid16) v += __bfloat162float(resid16[idx]);
                        if (C16) C16[idx] = __float2bfloat16(v);
                        if (C32) C32[idx] = v;
                    }
                }
            }
        }
    } else {
        const int seg = n0 >> 10;
        bf* dst = (seg == 0) ? C16 : ((seg == 1) ? C16b : C16c);
        const float* bseg = (seg == 0) ? bias : ((seg == 1) ? biasB : biasC);
        const int trans = (tstore >> seg) & 1;
        const int cb = n0 & 1023;
#pragma unroll
        for (int i = 0; i < 8; ++i) {
#pragma unroll
            for (int j = 0; j < 4; ++j) {
#pragma unroll
                for (int r = 0; r < 4; ++r) {
                    const int row = m0 + wm * 128 + i * 16 + qd * 4 + r;
                    const int col = cb + wn * 64 + j * 16 + fl;
                    float v = acc[i][j][r] * alpha + bseg[col];
                    const long idx = trans
                        ? (long)(row >> 11) * (1024L * 2048) + (long)col * 2048 + (row & 2047)
                        : (long)row * 1024 + col;
                    dst[idx] = __float2bfloat16(v);
                }
            }
        }
    }
#undef READ_A
#undef READ_B
#undef MFMA_Q
#undef SB
#undef BARS
#undef VMCNT6
#undef VMCNT0
#undef STG
}

// elementwise f32 -> bf16, n must be a multiple of 8
__global__ __launch_bounds__(256) void cast_f32_bf16(
    const float* __restrict__ in, bf* __restrict__ out, long n)
{
    long i = ((long)blockIdx.x * 256 + threadIdx.x) * 8;
    if (i >= n) return;
    float4 a = *(const float4*)(in + i);
    float4 b = *(const float4*)(in + i + 4);
    bf o[8] = {__float2bfloat16(a.x), __float2bfloat16(a.y),
               __float2bfloat16(a.z), __float2bfloat16(a.w),
               __float2bfloat16(b.x), __float2bfloat16(b.y),
               __float2bfloat16(b.z), __float2bfloat16(b.w)};
    *(bf16x8*)(out + i) = *(bf16x8*)o;
}

// W[R,C] f32 -> WT[C,R] bf16
__global__ __launch_bounds__(256) void transpose_f32_bf16(
    const float* __restrict__ in, bf* __restrict__ out, int R, int C)
{
    __shared__ bf t[32][33];
    const int c0 = blockIdx.x * 32, r0 = blockIdx.y * 32;
    const int tx = threadIdx.x, ty = threadIdx.y;
#pragma unroll
    for (int i = ty; i < 32; i += 8)
        t[i][tx] = __float2bfloat16(in[(long)(r0 + i) * C + c0 + tx]);
    __syncthreads();
#pragma unroll
    for (int i = ty; i < 32; i += 8)
        out[(long)(c0 + i) * R + r0 + tx] = t[tx][i];
}

// In-place row softmax over 2048 bf16 cols; one 256-thread block per row.
__global__ __launch_bounds__(256) void softmax_rows(bf* __restrict__ S)
{
    const long row = blockIdx.x;
    bf* p = S + row * 2048;
    const int tx = threadIdx.x;

    float v[8];
    float m = -3.0e38f;
#pragma unroll
    for (int i = 0; i < 8; i++) {
        v[i] = __bfloat162float(p[tx + 256 * i]);
        m = fmaxf(m, v[i]);
    }
    __shared__ float red[4];
#pragma unroll
    for (int o = 1; o < 64; o <<= 1) m = fmaxf(m, __shfl_xor(m, o, 64));
    if ((tx & 63) == 0) red[tx >> 6] = m;
    __syncthreads();
    m = fmaxf(fmaxf(red[0], red[1]), fmaxf(red[2], red[3]));

    float s = 0.f;
#pragma unroll
    for (int i = 0; i < 8; i++) { v[i] = __expf(v[i] - m); s += v[i]; }
#pragma unroll
    for (int o = 1; o < 64; o <<= 1) s += __shfl_xor(s, o, 64);
    __syncthreads();
    if ((tx & 63) == 0) red[tx >> 6] = s;
    __syncthreads();
    const float inv = 1.0f / (red[0] + red[1] + red[2] + red[3]);
#pragma unroll
    for (int i = 0; i < 8; i++) p[tx + 256 * i] = __float2bfloat16(v[i] * inv);
}

extern "C" void kernel_launch(void* const* d_in, const int* in_sizes, int n_in,
                              void* d_out, int out_size, void* d_ws, size_t ws_size,
                              hipStream_t stream)
{
    const int Bb = 8, Nn = 2048, DA = 768, DB = 1024;
    const long Mt = (long)Bb * Nn;   // 16384 tokens

    const float* x_a   = (const float*)d_in[0];
    const float* x_b   = (const float*)d_in[1];
    const float* sa_wq = (const float*)d_in[2];  const float* sa_bq = (const float*)d_in[3];
    const float* sa_wk = (const float*)d_in[4];  const float* sa_bk = (const float*)d_in[5];
    const float* sa_wv = (const float*)d_in[6];  const float* sa_bv = (const float*)d_in[7];
    const float* sa_wo = (const float*)d_in[8];  const float* sa_bo = (const float*)d_in[9];
    const float* ca_wq = (const float*)d_in[10]; const float* ca_bq = (const float*)d_in[11];
    const float* ca_wk = (const float*)d_in[12]; const float* ca_bk = (const float*)d_in[13];
    const float* ca_wv = (const float*)d_in[14]; const float* ca_bv = (const float*)d_in[15];
    const float* ca_wo = (const float*)d_in[16]; const float* ca_bo = (const float*)d_in[17];
    float* out = (float*)d_out;
    (void)in_sizes; (void)n_in; (void)out_size; (void)ws_size;

    // workspace carve-up (256B aligned): peak 207.5 MB (r3 layout proven)
    char* ws = (char*)d_ws;
    size_t off = 0;
    auto alloc = [&](size_t bytes) -> bf* {
        bf* p = (bf*)(ws + off);
        off += (bytes + 255) & ~(size_t)255;
        return p;
    };
    bf* wqkvT = alloc((size_t)3 * DB * DB * 2);  // [3072,1024] concat q,k,v
    bf* woT   = alloc((size_t)DB * DB * 2);
    bf* cwqT  = alloc((size_t)DB * DA * 2);      // [1024,768]
    bf* ckvT  = alloc((size_t)2 * DB * DB * 2);  // [2048,1024] concat k,v
    bf* cwoT  = alloc((size_t)DB * DB * 2);
    bf* slA   = alloc((size_t)Mt * DB * 2);      // xbB -> xaB -> VcT
    bf* slQ   = alloc((size_t)Mt * DB * 2);      // Q   -> Xb
    bf* slK   = alloc((size_t)Mt * DB * 2);      // K   -> attn -> Qc
    bf* slV   = alloc((size_t)Mt * DB * 2);      // VT  -> Kc
    bf* S     = alloc((size_t)Bb * Nn * Nn * 2);

    const dim3 tb(32, 8);
    const dim3 blk(256);
    const dim3 blk5(512);
    const long sQ = (long)Nn * DB;
    const long sS = (long)Nn * Nn;
    const float* nf = nullptr;
    const bf*    nb = nullptr;
    bf*          no = nullptr;

    // ---- ingestion: weight transposes (f32 -> bf16), concat layouts ----
    transpose_f32_bf16<<<dim3(DB/32, DB/32), tb, 0, stream>>>(sa_wq, wqkvT,                 DB, DB);
    transpose_f32_bf16<<<dim3(DB/32, DB/32), tb, 0, stream>>>(sa_wk, wqkvT + (size_t)DB*DB, DB, DB);
    transpose_f32_bf16<<<dim3(DB/32, DB/32), tb, 0, stream>>>(sa_wv, wqkvT + (size_t)2*DB*DB, DB, DB);
    transpose_f32_bf16<<<dim3(DB/32, DB/32), tb, 0, stream>>>(sa_wo, woT,  DB, DB);
    transpose_f32_bf16<<<dim3(DB/32, DA/32), tb, 0, stream>>>(ca_wq, cwqT, DA, DB);
    transpose_f32_bf16<<<dim3(DB/32, DB/32), tb, 0, stream>>>(ca_wk, ckvT,                 DB, DB);
    transpose_f32_bf16<<<dim3(DB/32, DB/32), tb, 0, stream>>>(ca_wv, ckvT + (size_t)DB*DB, DB, DB);
    transpose_f32_bf16<<<dim3(DB/32, DB/32), tb, 0, stream>>>(ca_wo, cwoT, DB, DB);

    // ---- self-attention ----
    cast_f32_bf16<<<dim3((unsigned)(Mt * DB / 8 / 256)), blk, 0, stream>>>(x_b, slA, Mt * DB);
    // fused QKV: Q->slQ, K->slK, V->slV (transposed per batch)
    gemm256<<<dim3(3*DB/256, Mt/256, 1), blk5, 0, stream>>>(
        slA, wqkvT, sa_bq, sa_bk, sa_bv, nf, nb, slQ, slK, slV, nullptr,
        (int)Mt, 3*DB, DB, 1.0f, 0, 0, 0, 0b100, 3);
    // scores = (Q @ K^T) / 32
    gemm256<<<dim3(Nn/256, Nn/256, Bb), blk5, 0, stream>>>(
        slQ, slK, nf, nf, nf, nf, nb, S, no, no, nullptr,
        Nn, Nn, DB, 0.03125f, sQ, sQ, sS, 0, 1);
    softmax_rows<<<dim3((unsigned)(Bb * Nn)), blk, 0, stream>>>(S);
    // attn = P @ V (VT as B^T) -> slK (K dead)
    gemm256<<<dim3(DB/256, Nn/256, Bb), blk5, 0, stream>>>(
        S, slV, nf, nf, nf, nf, nb, slK, no, no, nullptr,
        Nn, DB, Nn, 1.0f, sS, sQ, sQ, 0, 1);
    // x_b_new = x_b(f32) + attn @ Wo + bo -> slQ (Q dead)
    gemm256<<<dim3(DB/256, Mt/256, 1), blk5, 0, stream>>>(
        slK, woT, sa_bo, nf, nf, x_b, nb, slQ, no, no, nullptr,
        (int)Mt, DB, DB, 1.0f, 0, 0, 0, 0, 1);

    // ---- cross-attention ----
    cast_f32_bf16<<<dim3((unsigned)(Mt * DA / 8 / 256)), blk, 0, stream>>>(x_a, slA, Mt * DA);
    // Qc = xa @ cwq -> slK (attn dead)   [K=768 -> 12 K-tiles, 6 iters]
    gemm256<<<dim3(DB/256, Mt/256, 1), blk5, 0, stream>>>(
        slA, cwqT, ca_bq, nf, nf, nf, nb, slK, no, no, nullptr,
        (int)Mt, DB, DA, 1.0f, 0, 0, 0, 0, 1);
    // fused cKV from Xb(slQ): Kc->slV (VT dead), Vc->slA transposed (xaB dead)
    gemm256<<<dim3(2*DB/256, Mt/256, 1), blk5, 0, stream>>>(
        slQ, ckvT, ca_bk, ca_bv, nf, nf, nb, slV, slA, no, nullptr,
        (int)Mt, 2*DB, DB, 1.0f, 0, 0, 0, 0b10, 2);
    // scores = (Qc @ Kc^T) / sqrt(768)
    gemm256<<<dim3(Nn/256, Nn/256, Bb), blk5, 0, stream>>>(
        slK, slV, nf, nf, nf, nf, nb, S, no, no, nullptr,
        Nn, Nn, DB, 0.036084391824351615f, sQ, sQ, sS, 0, 1);
    softmax_rows<<<dim3((unsigned)(Bb * Nn)), blk, 0, stream>>>(S);
    // ca_attn = P @ Vc -> slV (Kc dead)
    gemm256<<<dim3(DB/256, Nn/256, Bb), blk5, 0, stream>>>(
        S, slA, nf, nf, nf, nf, nb, slV, no, no, nullptr,
        Nn, DB, Nn, 1.0f, sS, sQ, sQ, 0, 1);
    // out(f32) = x_b_new(bf16, slQ) + ca_attn @ Wo + bo
    gemm256<<<dim3(DB/256, Mt/256, 1), blk5, 0, stream>>>(
        slV, cwoT, ca_bo, nf, nf, nf, slQ, no, no, no, out,
        (int)Mt, DB, DB, 1.0f, 0, 0, 0, 0, 1);
}

// Round 4
// 1136.680 us; speedup vs baseline: 1.0090x; 1.0090x over previous
//
#include <hip/hip_runtime.h>
#include <hip/hip_bf16.h>

// Round 11: r9 post-mortem says the stall is NOT prefetch-count or L2
// locality (vmcnt 4->6 + XCD swizzle: no change; MfmaUtil stuck 23%).
// Theory: tail-latency coupling -- 1 block/CU, 8-wave lockstep, and a
// 2-slot double buffer caps the vmcnt wait-slack at ~1 tile-time, so every
// K-tile boundary eats the slowest load's L3/HBM tail twice. Fix: BK=32
// with a 4-slot LDS ring (4 x 32 KB = 128 KiB): staging runs 3 tiles
// ahead, the boundary vmcnt(8) targets loads issued ~2 tile-times earlier,
// and per-phase ds_read bursts drop to {6,2,4,0} (gray-code quadrant
// order, m201 shape). Restage hazard distance = 8 phases. Per-element
// K-accumulation order unchanged (ascending 32-chunks) -> bit-identical.
// f32 in/out per reference; bf16 MFMA internally. B=8, N=2048, DA=768, DB=1024.

#define AS1 __attribute__((address_space(1)))
#define AS3 __attribute__((address_space(3)))

typedef __attribute__((ext_vector_type(8))) short bf16x8;
typedef __attribute__((ext_vector_type(4))) float f32x4;

using bf = __hip_bfloat16;

// ---------------- unified 256x256 GEMM, BK=32, 4-slot ring ----------------
// C = alpha * A[M,K] @ BT[Nc,K]^T.
// nseg==1: (+bias)(+resid32/resid16) -> C16 and/or C32, ldc=Nc, tstore bit0.
// nseg>1 : 1024-col segments -> {C16,C16b,C16c} w/ biases {bias,biasB,biasC};
//          tstore bit s stores segment s transposed per 2048-row batch.
// Constraints: M%256==0, Nc%256==0, K%64==0, K>=128, gx*gy%8==0.
__global__ __launch_bounds__(512, 1) void gemm256(
    const bf* __restrict__ A, const bf* __restrict__ BT,
    const float* __restrict__ bias, const float* __restrict__ biasB,
    const float* __restrict__ biasC,
    const float* __restrict__ resid32, const bf* __restrict__ resid16,
    bf* __restrict__ C16, bf* __restrict__ C16b, bf* __restrict__ C16c,
    float* __restrict__ C32,
    int M, int Nc, int K, float alpha,
    long sA, long sB, long sC, int tstore, int nseg)
{
    // [slot:4][region:4][row:128][col:32] bf16 = 128 KiB.
    // region 0 = A rows [0,128), 1 = B rows [0,128), 2 = A rows [128,256),
    // region 3 = B rows [128,256). slot = K-tile & 3. Row = 64 B = 4 chunks.
    __shared__ __align__(16) char lds[131072];

    const int tid  = threadIdx.x;
    const int wave = tid >> 6;        // 0..7
    const int lane = tid & 63;
    const int wm = wave >> 2;         // 0..1 : M half (128 rows)
    const int wn = wave & 3;          // 0..3 : N quarter (64 cols)

    // XCD-aware bijective swizzle (T1; valid since gx*gy%8==0).
    const int gx = gridDim.x, gy = gridDim.y;
    int wg = blockIdx.y * gx + blockIdx.x;
    const int nwg = gx * gy;
    if (!(nwg & 7)) wg = (wg & 7) * (nwg >> 3) + (wg >> 3);
    const int m0 = (wg / gx) * 256;
    const int n0 = (wg % gx) * 256;

    const long zC = (long)blockIdx.z * sC;
    A  += (long)blockIdx.z * sA;
    BT += (long)blockIdx.z * sB;

    const int fl = lane & 15, qd = lane >> 4;
    const long ldb = (long)K * 2;

    // Staging: region = [128 rows x 32 cols] = 8 KB; wave covers rows
    // [wave*16, wave*16+16) = 1 KB = ONE global_load_lds. Lane -> (row,chunk):
    // row = lane>>2, chunk = lane&3. LDS dest linear; source chunk
    // pre-swizzled so LDS slot c of row R holds global chunk c ^ ((R>>1)&3).
    const int sRow = lane >> 2;
    const int sChk = (lane & 3) ^ ((lane >> 3) & 3);
    const char* gA = (const char*)A  + (long)(m0 + wave * 16 + sRow) * ldb + sChk * 16;
    const char* gB = (const char*)BT + (long)(n0 + wave * 16 + sRow) * ldb + sChk * 16;

    auto stage = [&](int t, int r) {   // K-tile t, region r
        const char* g = ((r & 1) ? gB : gA) + (long)((r >> 1) * 128) * ldb + (long)t * 64;
        char* l = lds + (t & 3) * 32768 + r * 8192 + wave * 1024;
        __builtin_amdgcn_global_load_lds((const AS1 void*)g, (AS3 void*)l, 16, 0, 0);
    };

    // Fragment reads: row R (R&15 == fl for all fragment rows), k-chunk qd
    // lives at slot qd ^ ((R>>1)&3) = qd ^ ((fl>>1)&3). 2-way bank (free).
    const int soff = ((qd ^ ((fl >> 1) & 3)) * 16);
    const char* Abase = lds + (wm ? 2 : 0) * 8192 + fl * 64 + soff;
    const char* Bbase = lds + ((wn >> 1) ? 3 : 1) * 8192 + (wn & 1) * 4096 + fl * 64 + soff;

    f32x4 acc[8][4];
#pragma unroll
    for (int i = 0; i < 8; ++i)
#pragma unroll
        for (int j = 0; j < 4; ++j)
            acc[i][j] = (f32x4){0.f, 0.f, 0.f, 0.f};

    bf16x8 aLo[4], aHi[4], bLo[2], bHi[2];

#define RD_ALO(SL) { const char* p_ = Abase + (SL) * 32768; \
    _Pragma("unroll") for (int f_ = 0; f_ < 4; ++f_) aLo[f_] = *(const bf16x8*)(p_ + f_ * 1024); }
#define RD_AHI(SL) { const char* p_ = Abase + (SL) * 32768 + 4096; \
    _Pragma("unroll") for (int f_ = 0; f_ < 4; ++f_) aHi[f_] = *(const bf16x8*)(p_ + f_ * 1024); }
#define RD_BLO(SL) { const char* p_ = Bbase + (SL) * 32768; \
    _Pragma("unroll") for (int g_ = 0; g_ < 2; ++g_) bLo[g_] = *(const bf16x8*)(p_ + g_ * 1024); }
#define RD_BHI(SL) { const char* p_ = Bbase + (SL) * 32768 + 2048; \
    _Pragma("unroll") for (int g_ = 0; g_ < 2; ++g_) bHi[g_] = *(const bf16x8*)(p_ + g_ * 1024); }

// 8 MFMA: A frags FR (array, row offset RO) x B frags GR (col offset CO)
#define MFMA8(FR, RO, GR, CO) { \
    __builtin_amdgcn_s_setprio(1); \
    _Pragma("unroll") for (int f_ = 0; f_ < 4; ++f_) \
    _Pragma("unroll") for (int g_ = 0; g_ < 2; ++g_) \
        acc[(RO) + f_][(CO) + g_] = __builtin_amdgcn_mfma_f32_16x16x32_bf16( \
            FR[f_], GR[g_], acc[(RO) + f_][(CO) + g_], 0, 0, 0); \
    __builtin_amdgcn_s_setprio(0); }

#define SB()  __builtin_amdgcn_sched_barrier(0)
#define BARS() { SB(); __builtin_amdgcn_s_barrier(); SB(); }
#define VMC(N) asm volatile("s_waitcnt vmcnt(" #N ")" ::: "memory")

    const int NT = K >> 5;     // K-tiles of 32 (>= 24 at all call sites)

    // Prologue: stage tiles 0,1,2 (12 loads/wave); vmcnt(8) -> tile 0 landed.
#pragma unroll
    for (int t = 0; t < 3; ++t)
#pragma unroll
        for (int r = 0; r < 4; ++r) stage(t, r);
    VMC(8);
    BARS();

    for (int t = 0; t < NT; ++t) {
        const int st = t + 3;              // stage 3 tiles ahead
        const int sl = t & 3;
        const bool sOK = st < NT;
        // ph1: read aLo,bLo (6); stage st.r0
        RD_ALO(sl); RD_BLO(sl);
        if (sOK) stage(st, 0);
        BARS();
        MFMA8(aLo, 0, bLo, 0);
        // ph2: read bHi (2); stage st.r1
        RD_BHI(sl);
        if (sOK) stage(st, 1);
        BARS();
        MFMA8(aLo, 0, bHi, 2);
        // ph3: read aHi (4); stage st.r2
        RD_AHI(sl);
        if (sOK) stage(st, 2);
        BARS();
        MFMA8(aHi, 4, bHi, 2);
        // ph4: stage st.r3; boundary wait: tile t+1 must be landed.
        if (sOK) stage(st, 3);
        if (t < NT - 3)       { VMC(8); }
        else if (t == NT - 3) { VMC(4); }
        else                  { VMC(0); }
        BARS();
        MFMA8(aHi, 4, bLo, 0);
    }

    // Epilogue: C/D layout col = lane&15, row = qd*4 + r (verified m89/m91).
    if (nseg == 1) {
        const long ldc = Nc;
#pragma unroll
        for (int i = 0; i < 8; ++i) {
#pragma unroll
            for (int j = 0; j < 4; ++j) {
#pragma unroll
                for (int r = 0; r < 4; ++r) {
                    const int row = m0 + wm * 128 + i * 16 + qd * 4 + r;
                    const int col = n0 + wn * 64 + j * 16 + fl;
                    float v = acc[i][j][r] * alpha;
                    if (bias) v += bias[col];
                    if (tstore & 1) {
                        const long idx = (long)(row >> 11) * ((long)Nc * 2048)
                                       + (long)col * 2048 + (row & 2047);
                        C16[idx] = __float2bfloat16(v);
                    } else {
                        const long idx = zC + (long)row * ldc + col;
                        if (resid32) v += resid32[idx];
                        if (resid16) v += __bfloat162float(resid16[idx]);
                        if (C16) C16[idx] = __float2bfloat16(v);
                        if (C32) C32[idx] = v;
                    }
                }
            }
        }
    } else {
        const int seg = n0 >> 10;
        bf* dst = (seg == 0) ? C16 : ((seg == 1) ? C16b : C16c);
        const float* bseg = (seg == 0) ? bias : ((seg == 1) ? biasB : biasC);
        const int trans = (tstore >> seg) & 1;
        const int cb = n0 & 1023;
#pragma unroll
        for (int i = 0; i < 8; ++i) {
#pragma unroll
            for (int j = 0; j < 4; ++j) {
#pragma unroll
                for (int r = 0; r < 4; ++r) {
                    const int row = m0 + wm * 128 + i * 16 + qd * 4 + r;
                    const int col = cb + wn * 64 + j * 16 + fl;
                    float v = acc[i][j][r] * alpha + bseg[col];
                    const long idx = trans
                        ? (long)(row >> 11) * (1024L * 2048) + (long)col * 2048 + (row & 2047)
                        : (long)row * 1024 + col;
                    dst[idx] = __float2bfloat16(v);
                }
            }
        }
    }
#undef RD_ALO
#undef RD_AHI
#undef RD_BLO
#undef RD_BHI
#undef MFMA8
#undef SB
#undef BARS
#undef VMC
}

// elementwise f32 -> bf16, n must be a multiple of 8
__global__ __launch_bounds__(256) void cast_f32_bf16(
    const float* __restrict__ in, bf* __restrict__ out, long n)
{
    long i = ((long)blockIdx.x * 256 + threadIdx.x) * 8;
    if (i >= n) return;
    float4 a = *(const float4*)(in + i);
    float4 b = *(const float4*)(in + i + 4);
    bf o[8] = {__float2bfloat16(a.x), __float2bfloat16(a.y),
               __float2bfloat16(a.z), __float2bfloat16(a.w),
               __float2bfloat16(b.x), __float2bfloat16(b.y),
               __float2bfloat16(b.z), __float2bfloat16(b.w)};
    *(bf16x8*)(out + i) = *(bf16x8*)o;
}

// W[R,C] f32 -> WT[C,R] bf16
__global__ __launch_bounds__(256) void transpose_f32_bf16(
    const float* __restrict__ in, bf* __restrict__ out, int R, int C)
{
    __shared__ bf t[32][33];
    const int c0 = blockIdx.x * 32, r0 = blockIdx.y * 32;
    const int tx = threadIdx.x, ty = threadIdx.y;
#pragma unroll
    for (int i = ty; i < 32; i += 8)
        t[i][tx] = __float2bfloat16(in[(long)(r0 + i) * C + c0 + tx]);
    __syncthreads();
#pragma unroll
    for (int i = ty; i < 32; i += 8)
        out[(long)(c0 + i) * R + r0 + tx] = t[tx][i];
}

// In-place row softmax over 2048 bf16 cols; one 256-thread block per row.
__global__ __launch_bounds__(256) void softmax_rows(bf* __restrict__ S)
{
    const long row = blockIdx.x;
    bf* p = S + row * 2048;
    const int tx = threadIdx.x;

    float v[8];
    float m = -3.0e38f;
#pragma unroll
    for (int i = 0; i < 8; i++) {
        v[i] = __bfloat162float(p[tx + 256 * i]);
        m = fmaxf(m, v[i]);
    }
    __shared__ float red[4];
#pragma unroll
    for (int o = 1; o < 64; o <<= 1) m = fmaxf(m, __shfl_xor(m, o, 64));
    if ((tx & 63) == 0) red[tx >> 6] = m;
    __syncthreads();
    m = fmaxf(fmaxf(red[0], red[1]), fmaxf(red[2], red[3]));

    float s = 0.f;
#pragma unroll
    for (int i = 0; i < 8; i++) { v[i] = __expf(v[i] - m); s += v[i]; }
#pragma unroll
    for (int o = 1; o < 64; o <<= 1) s += __shfl_xor(s, o, 64);
    __syncthreads();
    if ((tx & 63) == 0) red[tx >> 6] = s;
    __syncthreads();
    const float inv = 1.0f / (red[0] + red[1] + red[2] + red[3]);
#pragma unroll
    for (int i = 0; i < 8; i++) p[tx + 256 * i] = __float2bfloat16(v[i] * inv);
}

extern "C" void kernel_launch(void* const* d_in, const int* in_sizes, int n_in,
                              void* d_out, int out_size, void* d_ws, size_t ws_size,
                              hipStream_t stream)
{
    const int Bb = 8, Nn = 2048, DA = 768, DB = 1024;
    const long Mt = (long)Bb * Nn;   // 16384 tokens

    const float* x_a   = (const float*)d_in[0];
    const float* x_b   = (const float*)d_in[1];
    const float* sa_wq = (const float*)d_in[2];  const float* sa_bq = (const float*)d_in[3];
    const float* sa_wk = (const float*)d_in[4];  const float* sa_bk = (const float*)d_in[5];
    const float* sa_wv = (const float*)d_in[6];  const float* sa_bv = (const float*)d_in[7];
    const float* sa_wo = (const float*)d_in[8];  const float* sa_bo = (const float*)d_in[9];
    const float* ca_wq = (const float*)d_in[10]; const float* ca_bq = (const float*)d_in[11];
    const float* ca_wk = (const float*)d_in[12]; const float* ca_bk = (const float*)d_in[13];
    const float* ca_wv = (const float*)d_in[14]; const float* ca_bv = (const float*)d_in[15];
    const float* ca_wo = (const float*)d_in[16]; const float* ca_bo = (const float*)d_in[17];
    float* out = (float*)d_out;
    (void)in_sizes; (void)n_in; (void)out_size; (void)ws_size;

    // workspace carve-up (256B aligned): peak 207.5 MB (r3 layout proven)
    char* ws = (char*)d_ws;
    size_t off = 0;
    auto alloc = [&](size_t bytes) -> bf* {
        bf* p = (bf*)(ws + off);
        off += (bytes + 255) & ~(size_t)255;
        return p;
    };
    bf* wqkvT = alloc((size_t)3 * DB * DB * 2);  // [3072,1024] concat q,k,v
    bf* woT   = alloc((size_t)DB * DB * 2);
    bf* cwqT  = alloc((size_t)DB * DA * 2);      // [1024,768]
    bf* ckvT  = alloc((size_t)2 * DB * DB * 2);  // [2048,1024] concat k,v
    bf* cwoT  = alloc((size_t)DB * DB * 2);
    bf* slA   = alloc((size_t)Mt * DB * 2);      // xbB -> xaB -> VcT
    bf* slQ   = alloc((size_t)Mt * DB * 2);      // Q   -> Xb
    bf* slK   = alloc((size_t)Mt * DB * 2);      // K   -> attn -> Qc
    bf* slV   = alloc((size_t)Mt * DB * 2);      // VT  -> Kc
    bf* S     = alloc((size_t)Bb * Nn * Nn * 2);

    const dim3 tb(32, 8);
    const dim3 blk(256);
    const dim3 blk5(512);
    const long sQ = (long)Nn * DB;
    const long sS = (long)Nn * Nn;
    const float* nf = nullptr;
    const bf*    nb = nullptr;
    bf*          no = nullptr;

    // ---- ingestion: weight transposes (f32 -> bf16), concat layouts ----
    transpose_f32_bf16<<<dim3(DB/32, DB/32), tb, 0, stream>>>(sa_wq, wqkvT,                 DB, DB);
    transpose_f32_bf16<<<dim3(DB/32, DB/32), tb, 0, stream>>>(sa_wk, wqkvT + (size_t)DB*DB, DB, DB);
    transpose_f32_bf16<<<dim3(DB/32, DB/32), tb, 0, stream>>>(sa_wv, wqkvT + (size_t)2*DB*DB, DB, DB);
    transpose_f32_bf16<<<dim3(DB/32, DB/32), tb, 0, stream>>>(sa_wo, woT,  DB, DB);
    transpose_f32_bf16<<<dim3(DB/32, DA/32), tb, 0, stream>>>(ca_wq, cwqT, DA, DB);
    transpose_f32_bf16<<<dim3(DB/32, DB/32), tb, 0, stream>>>(ca_wk, ckvT,                 DB, DB);
    transpose_f32_bf16<<<dim3(DB/32, DB/32), tb, 0, stream>>>(ca_wv, ckvT + (size_t)DB*DB, DB, DB);
    transpose_f32_bf16<<<dim3(DB/32, DB/32), tb, 0, stream>>>(ca_wo, cwoT, DB, DB);

    // ---- self-attention ----
    cast_f32_bf16<<<dim3((unsigned)(Mt * DB / 8 / 256)), blk, 0, stream>>>(x_b, slA, Mt * DB);
    // fused QKV: Q->slQ, K->slK, V->slV (transposed per batch)
    gemm256<<<dim3(3*DB/256, Mt/256, 1), blk5, 0, stream>>>(
        slA, wqkvT, sa_bq, sa_bk, sa_bv, nf, nb, slQ, slK, slV, nullptr,
        (int)Mt, 3*DB, DB, 1.0f, 0, 0, 0, 0b100, 3);
    // scores = (Q @ K^T) / 32
    gemm256<<<dim3(Nn/256, Nn/256, Bb), blk5, 0, stream>>>(
        slQ, slK, nf, nf, nf, nf, nb, S, no, no, nullptr,
        Nn, Nn, DB, 0.03125f, sQ, sQ, sS, 0, 1);
    softmax_rows<<<dim3((unsigned)(Bb * Nn)), blk, 0, stream>>>(S);
    // attn = P @ V (VT as B^T) -> slK (K dead)
    gemm256<<<dim3(DB/256, Nn/256, Bb), blk5, 0, stream>>>(
        S, slV, nf, nf, nf, nf, nb, slK, no, no, nullptr,
        Nn, DB, Nn, 1.0f, sS, sQ, sQ, 0, 1);
    // x_b_new = x_b(f32) + attn @ Wo + bo -> slQ (Q dead)
    gemm256<<<dim3(DB/256, Mt/256, 1), blk5, 0, stream>>>(
        slK, woT, sa_bo, nf, nf, x_b, nb, slQ, no, no, nullptr,
        (int)Mt, DB, DB, 1.0f, 0, 0, 0, 0, 1);

    // ---- cross-attention ----
    cast_f32_bf16<<<dim3((unsigned)(Mt * DA / 8 / 256)), blk, 0, stream>>>(x_a, slA, Mt * DA);
    // Qc = xa @ cwq -> slK (attn dead)   [K=768 -> 24 K-tiles]
    gemm256<<<dim3(DB/256, Mt/256, 1), blk5, 0, stream>>>(
        slA, cwqT, ca_bq, nf, nf, nf, nb, slK, no, no, nullptr,
        (int)Mt, DB, DA, 1.0f, 0, 0, 0, 0, 1);
    // fused cKV from Xb(slQ): Kc->slV (VT dead), Vc->slA transposed (xaB dead)
    gemm256<<<dim3(2*DB/256, Mt/256, 1), blk5, 0, stream>>>(
        slQ, ckvT, ca_bk, ca_bv, nf, nf, nb, slV, slA, no, nullptr,
        (int)Mt, 2*DB, DB, 1.0f, 0, 0, 0, 0b10, 2);
    // scores = (Qc @ Kc^T) / sqrt(768)
    gemm256<<<dim3(Nn/256, Nn/256, Bb), blk5, 0, stream>>>(
        slK, slV, nf, nf, nf, nf, nb, S, no, no, nullptr,
        Nn, Nn, DB, 0.036084391824351615f, sQ, sQ, sS, 0, 1);
    softmax_rows<<<dim3((unsigned)(Bb * Nn)), blk, 0, stream>>>(S);
    // ca_attn = P @ Vc -> slV (Kc dead)
    gemm256<<<dim3(DB/256, Nn/256, Bb), blk5, 0, stream>>>(
        S, slA, nf, nf, nf, nf, nb, slV, no, no, nullptr,
        Nn, DB, Nn, 1.0f, sS, sQ, sQ, 0, 1);
    // out(f32) = x_b_new(bf16, slQ) + ca_attn @ Wo + bo
    gemm256<<<dim3(DB/256, Mt/256, 1), blk5, 0, stream>>>(
        slV, cwoT, ca_bo, nf, nf, nf, slQ, no, no, no, out,
        (int)Mt, DB, DB, 1.0f, 0, 0, 0, 0, 1);
}

// Round 5
// 1109.366 us; speedup vs baseline: 1.0338x; 1.0246x over previous
//
#include <hip/hip_runtime.h>
#include <hip/hip_bf16.h>

// Round 12: faithful m201 8-phase port. r0/r9/r11 refuted occupancy/depth/
// tail theories (MfmaUtil pinned 23-25% across 4 schedules). Deltas vs r8-r11,
// copied from the verified-62% template: two s_barriers per phase (MFMA
// cluster isolated; ds_reads issue pre-barrier), read-ahead one phase with
// compiler-counted lgkm waits (NO sched_barrier(0) -- m141: SB regresses),
// 8-read phases in gray quadrant order (A-set held 2 phases), vmcnt(6) at
// phases 3/7 only with the cover rule: any read of freshly staged data is
// separated from its covering vmcnt by >=1 barrier (r11 violated this for
// cross-wave stages). 2 K-tiles/iter, 2-dbuf, 2 loads per phase per wave.
// Numerics: K ascending, khalf 0 then 1 per acc -> bit-identical to r8-r11.
// f32 in/out per reference; bf16 MFMA internally. B=8, N=2048, DA=768, DB=1024.

#define AS1 __attribute__((address_space(1)))
#define AS3 __attribute__((address_space(3)))

typedef __attribute__((ext_vector_type(8))) short bf16x8;
typedef __attribute__((ext_vector_type(4))) float f32x4;

using bf = __hip_bfloat16;

// ---------------- unified 256x256 8-phase GEMM (BK=64, 2 tiles/iter) -------
// C = alpha * A[M,K] @ BT[Nc,K]^T.
// nseg==1: (+bias)(+resid32/resid16) -> C16 and/or C32, ldc=Nc, tstore bit0.
// nseg>1 : 1024-col segments -> {C16,C16b,C16c} w/ biases {bias,biasB,biasC};
//          tstore bit s stores segment s transposed per 2048-row batch.
// Constraints: M%256==0, Nc%256==0, K%128==0, gx*gy%8==0 (all sites satisfy).
__global__ __launch_bounds__(512, 1) void gemm256(
    const bf* __restrict__ A, const bf* __restrict__ BT,
    const float* __restrict__ bias, const float* __restrict__ biasB,
    const float* __restrict__ biasC,
    const float* __restrict__ resid32, const bf* __restrict__ resid16,
    bf* __restrict__ C16, bf* __restrict__ C16b, bf* __restrict__ C16c,
    float* __restrict__ C32,
    int M, int Nc, int K, float alpha,
    long sA, long sB, long sC, int tstore, int nseg)
{
    // [buf:2][mat:2][half:2][row:128][col:64] bf16 = 128 KiB.
    // mat 0 = A, 1 = B; half h = rows [h*128, h*128+128) of the 256-tile.
    __shared__ __align__(16) char lds[131072];

    const int tid  = threadIdx.x;
    const int wave = tid >> 6;        // 0..7
    const int lane = tid & 63;
    const int wm = wave >> 2;         // 0..1 : M half (128 rows)
    const int wn = wave & 3;          // 0..3 : N quarter (64 cols)

    // XCD-aware bijective swizzle (T1; valid since gx*gy%8==0).
    const int gx = gridDim.x, gy = gridDim.y;
    int wg = blockIdx.y * gx + blockIdx.x;
    const int nwg = gx * gy;
    if (!(nwg & 7)) wg = (wg & 7) * (nwg >> 3) + (wg >> 3);
    const int m0 = (wg / gx) * 256;
    const int n0 = (wg % gx) * 256;

    const long zC = (long)blockIdx.z * sC;
    A  += (long)blockIdx.z * sA;
    BT += (long)blockIdx.z * sB;

    const int fl = lane & 15, qd = lane >> 4;
    const long ldb = (long)K * 2;

    // Staging: half-tile = [128 rows][64 cols] = 16 KB; per wave 2 loads of
    // 8 rows (1 KB each): rows wave*8+(lane>>3) and 64+wave*8+(lane>>3).
    // LDS dest linear; source chunk pre-swizzled: LDS slot s of row R holds
    // global chunk s ^ (R&7); R&7 == lane>>3 for staging lanes.
    const int scn = (lane & 7) ^ (lane >> 3);
    const char* gA = (const char*)A  + (long)(m0 + (lane >> 3)) * ldb + scn * 16;
    const char* gB = (const char*)BT + (long)(n0 + (lane >> 3)) * ldb + scn * 16;

    auto stage = [&](int mat, int h, int t) {   // half-tile (mat,h) of K-tile t
        const char* g = (mat ? gB : gA) + (long)(h * 128 + wave * 8) * ldb + (long)t * 128;
        char* l = lds + (t & 1) * 65536 + mat * 32768 + h * 16384 + wave * 1024;
        __builtin_amdgcn_global_load_lds((const AS1 void*)g,            (AS3 void*)l,        16, 0, 0);
        __builtin_amdgcn_global_load_lds((const AS1 void*)(g + 64*ldb), (AS3 void*)(l + 8192), 16, 0, 0);
    };

    // Fragment reads: k-chunk c = h*4+qd of row R lives at slot c^(R&7);
    // R&7 == fl&7 for all fragment rows. 2-way bank aliasing only (free).
    const int s0slot = qd ^ (fl & 7);
    const int so0 = s0slot * 16;
    const int so1 = (s0slot ^ 4) * 16;
    const char* AbH0 = lds + wm * 16384 + fl * 128 + so0;
    const char* AbH1 = lds + wm * 16384 + fl * 128 + so1;
    const char* BbH0 = lds + 32768 + (wn >> 1) * 16384 + (wn & 1) * 8192 + fl * 128 + so0;
    const char* BbH1 = lds + 32768 + (wn >> 1) * 16384 + (wn & 1) * 8192 + fl * 128 + so1;

    f32x4 acc[8][4];
#pragma unroll
    for (int i = 0; i < 8; ++i)
#pragma unroll
        for (int j = 0; j < 4; ++j)
            acc[i][j] = (f32x4){0.f, 0.f, 0.f, 0.f};

    bf16x8 aA[4][2], aB[4][2];          // A quadrant frag sets [frag][khalf]
    bf16x8 bP[2][2], bN[2][2], bQ1[2][2];  // B frag sets

#define RD_A(dst, SL, mq) { \
    const char* pa0_ = AbH0 + (SL) * 65536 + (mq) * 8192; \
    const char* pa1_ = AbH1 + (SL) * 65536 + (mq) * 8192; \
    _Pragma("unroll") for (int f_ = 0; f_ < 4; ++f_) { \
        dst[f_][0] = *(const bf16x8*)(pa0_ + f_ * 2048); \
        dst[f_][1] = *(const bf16x8*)(pa1_ + f_ * 2048); } }

#define RD_B(dst, SL, nq) { \
    const char* pb0_ = BbH0 + (SL) * 65536 + (nq) * 4096; \
    const char* pb1_ = BbH1 + (SL) * 65536 + (nq) * 4096; \
    _Pragma("unroll") for (int g_ = 0; g_ < 2; ++g_) { \
        dst[g_][0] = *(const bf16x8*)(pb0_ + g_ * 2048); \
        dst[g_][1] = *(const bf16x8*)(pb1_ + g_ * 2048); } }

#define MFMA_Q(AF, BF, mq, nq) { \
    __builtin_amdgcn_s_setprio(1); \
    _Pragma("unroll") for (int f_ = 0; f_ < 4; ++f_) \
    _Pragma("unroll") for (int g_ = 0; g_ < 2; ++g_) \
    _Pragma("unroll") for (int h_ = 0; h_ < 2; ++h_) \
        acc[(mq)*4+f_][(nq)*2+g_] = __builtin_amdgcn_mfma_f32_16x16x32_bf16( \
            AF[f_][h_], BF[g_][h_], acc[(mq)*4+f_][(nq)*2+g_], 0, 0, 0); \
    __builtin_amdgcn_s_setprio(0); }

#define BAR() __builtin_amdgcn_s_barrier()
#define VMC(N) asm volatile("s_waitcnt vmcnt(" #N ")" ::: "memory")

    const int NT    = K >> 6;     // K-tiles (even at all call sites)
    const int niter = NT >> 1;

    // Prologue: stage tiles 0,1 fully (8 half-tiles, 16 loads/wave);
    // vmcnt(6) -> tile0 + tile1.A0 landed, {t1.B0, t1.A1, t1.B1} in flight
    // (== steady-state post-ph7 ledger). Barrier separates cover from reads.
#pragma unroll
    for (int t = 0; t < 2; ++t) {
        stage(0, 0, t); stage(1, 0, t); stage(0, 1, t); stage(1, 1, t);
    }
    VMC(6);
    BAR();
    RD_A(aA, 0, 0);                // A0(tile0)

    for (int I = 0; I < niter; ++I) {
        const int t2a = 2 * I + 2, t2b = 2 * I + 3;
        const bool sa = t2a < NT;  // false only in the last iteration
        // ph0: Q0(b0) = (aA, bP); reads same-phase bP + ahead bQ1
        RD_B(bP, 0, 0); RD_B(bQ1, 0, 1);
        if (sa) stage(0, 0, t2a);
        BAR(); MFMA_Q(aA, bP, 0, 0); BAR();
        // ph1: Q1(b0) = (aA, bQ1); read ahead A1(b0)
        RD_A(aB, 0, 1);
        if (sa) stage(1, 0, t2a);
        BAR(); MFMA_Q(aA, bQ1, 0, 1); BAR();
        // ph2: Q2(b0) = (aB, bQ1); read ahead A0(b1)
        RD_A(aA, 1, 0);
        if (sa) stage(0, 1, t2a);
        BAR(); MFMA_Q(aB, bQ1, 1, 1); BAR();
        // ph3: Q3(b0) = (aB, bP); counted vmcnt covers prev{B0,A1,B1}(b1) + A0(b0')
        if (sa) { stage(1, 1, t2a); VMC(6); } else { VMC(0); }
        BAR(); MFMA_Q(aB, bP, 1, 0); BAR();
        // ph4: Q0(b1) = (aA, bN); reads same-phase bN + ahead bQ1 (covered by ph3)
        RD_B(bN, 1, 0); RD_B(bQ1, 1, 1);
        if (sa) stage(0, 0, t2b);
        BAR(); MFMA_Q(aA, bN, 0, 0); BAR();
        // ph5: Q1(b1); read ahead A1(b1)
        RD_A(aB, 1, 1);
        if (sa) stage(1, 0, t2b);
        BAR(); MFMA_Q(aA, bQ1, 0, 1); BAR();
        // ph6: Q2(b1); read ahead A0(next b0) (covered by ph3 vmcnt)
        if (sa) { RD_A(aA, 0, 0); stage(0, 1, t2b); }
        BAR(); MFMA_Q(aB, bQ1, 1, 1); BAR();
        // ph7: Q3(b1); counted vmcnt for next iteration's cover
        if (sa) { stage(1, 1, t2b); VMC(6); }
        BAR(); MFMA_Q(aB, bN, 1, 0); BAR();
    }

    // Epilogue: C/D layout col = lane&15, row = qd*4 + r (verified m89/m91).
    if (nseg == 1) {
        const long ldc = Nc;
#pragma unroll
        for (int i = 0; i < 8; ++i) {
#pragma unroll
            for (int j = 0; j < 4; ++j) {
#pragma unroll
                for (int r = 0; r < 4; ++r) {
                    const int row = m0 + wm * 128 + i * 16 + qd * 4 + r;
                    const int col = n0 + wn * 64 + j * 16 + fl;
                    float v = acc[i][j][r] * alpha;
                    if (bias) v += bias[col];
                    if (tstore & 1) {
                        const long idx = (long)(row >> 11) * ((long)Nc * 2048)
                                       + (long)col * 2048 + (row & 2047);
                        C16[idx] = __float2bfloat16(v);
                    } else {
                        const long idx = zC + (long)row * ldc + col;
                        if (resid32) v += resid32[idx];
                        if (resid16) v += __bfloat162float(resid16[idx]);
                        if (C16) C16[idx] = __float2bfloat16(v);
                        if (C32) C32[idx] = v;
                    }
                }
            }
        }
    } else {
        const int seg = n0 >> 10;
        bf* dst = (seg == 0) ? C16 : ((seg == 1) ? C16b : C16c);
        const float* bseg = (seg == 0) ? bias : ((seg == 1) ? biasB : biasC);
        const int trans = (tstore >> seg) & 1;
        const int cb = n0 & 1023;
#pragma unroll
        for (int i = 0; i < 8; ++i) {
#pragma unroll
            for (int j = 0; j < 4; ++j) {
#pragma unroll
                for (int r = 0; r < 4; ++r) {
                    const int row = m0 + wm * 128 + i * 16 + qd * 4 + r;
                    const int col = cb + wn * 64 + j * 16 + fl;
                    float v = acc[i][j][r] * alpha + bseg[col];
                    const long idx = trans
                        ? (long)(row >> 11) * (1024L * 2048) + (long)col * 2048 + (row & 2047)
                        : (long)row * 1024 + col;
                    dst[idx] = __float2bfloat16(v);
                }
            }
        }
    }
#undef RD_A
#undef RD_B
#undef MFMA_Q
#undef BAR
#undef VMC
}

// elementwise f32 -> bf16, n must be a multiple of 8
__global__ __launch_bounds__(256) void cast_f32_bf16(
    const float* __restrict__ in, bf* __restrict__ out, long n)
{
    long i = ((long)blockIdx.x * 256 + threadIdx.x) * 8;
    if (i >= n) return;
    float4 a = *(const float4*)(in + i);
    float4 b = *(const float4*)(in + i + 4);
    bf o[8] = {__float2bfloat16(a.x), __float2bfloat16(a.y),
               __float2bfloat16(a.z), __float2bfloat16(a.w),
               __float2bfloat16(b.x), __float2bfloat16(b.y),
               __float2bfloat16(b.z), __float2bfloat16(b.w)};
    *(bf16x8*)(out + i) = *(bf16x8*)o;
}

// W[R,C] f32 -> WT[C,R] bf16
__global__ __launch_bounds__(256) void transpose_f32_bf16(
    const float* __restrict__ in, bf* __restrict__ out, int R, int C)
{
    __shared__ bf t[32][33];
    const int c0 = blockIdx.x * 32, r0 = blockIdx.y * 32;
    const int tx = threadIdx.x, ty = threadIdx.y;
#pragma unroll
    for (int i = ty; i < 32; i += 8)
        t[i][tx] = __float2bfloat16(in[(long)(r0 + i) * C + c0 + tx]);
    __syncthreads();
#pragma unroll
    for (int i = ty; i < 32; i += 8)
        out[(long)(c0 + i) * R + r0 + tx] = t[tx][i];
}

// In-place row softmax over 2048 bf16 cols; one 256-thread block per row.
__global__ __launch_bounds__(256) void softmax_rows(bf* __restrict__ S)
{
    const long row = blockIdx.x;
    bf* p = S + row * 2048;
    const int tx = threadIdx.x;

    float v[8];
    float m = -3.0e38f;
#pragma unroll
    for (int i = 0; i < 8; i++) {
        v[i] = __bfloat162float(p[tx + 256 * i]);
        m = fmaxf(m, v[i]);
    }
    __shared__ float red[4];
#pragma unroll
    for (int o = 1; o < 64; o <<= 1) m = fmaxf(m, __shfl_xor(m, o, 64));
    if ((tx & 63) == 0) red[tx >> 6] = m;
    __syncthreads();
    m = fmaxf(fmaxf(red[0], red[1]), fmaxf(red[2], red[3]));

    float s = 0.f;
#pragma unroll
    for (int i = 0; i < 8; i++) { v[i] = __expf(v[i] - m); s += v[i]; }
#pragma unroll
    for (int o = 1; o < 64; o <<= 1) s += __shfl_xor(s, o, 64);
    __syncthreads();
    if ((tx & 63) == 0) red[tx >> 6] = s;
    __syncthreads();
    const float inv = 1.0f / (red[0] + red[1] + red[2] + red[3]);
#pragma unroll
    for (int i = 0; i < 8; i++) p[tx + 256 * i] = __float2bfloat16(v[i] * inv);
}

extern "C" void kernel_launch(void* const* d_in, const int* in_sizes, int n_in,
                              void* d_out, int out_size, void* d_ws, size_t ws_size,
                              hipStream_t stream)
{
    const int Bb = 8, Nn = 2048, DA = 768, DB = 1024;
    const long Mt = (long)Bb * Nn;   // 16384 tokens

    const float* x_a   = (const float*)d_in[0];
    const float* x_b   = (const float*)d_in[1];
    const float* sa_wq = (const float*)d_in[2];  const float* sa_bq = (const float*)d_in[3];
    const float* sa_wk = (const float*)d_in[4];  const float* sa_bk = (const float*)d_in[5];
    const float* sa_wv = (const float*)d_in[6];  const float* sa_bv = (const float*)d_in[7];
    const float* sa_wo = (const float*)d_in[8];  const float* sa_bo = (const float*)d_in[9];
    const float* ca_wq = (const float*)d_in[10]; const float* ca_bq = (const float*)d_in[11];
    const float* ca_wk = (const float*)d_in[12]; const float* ca_bk = (const float*)d_in[13];
    const float* ca_wv = (const float*)d_in[14]; const float* ca_bv = (const float*)d_in[15];
    const float* ca_wo = (const float*)d_in[16]; const float* ca_bo = (const float*)d_in[17];
    float* out = (float*)d_out;
    (void)in_sizes; (void)n_in; (void)out_size; (void)ws_size;

    // workspace carve-up (256B aligned): peak 207.5 MB (r3 layout proven)
    char* ws = (char*)d_ws;
    size_t off = 0;
    auto alloc = [&](size_t bytes) -> bf* {
        bf* p = (bf*)(ws + off);
        off += (bytes + 255) & ~(size_t)255;
        return p;
    };
    bf* wqkvT = alloc((size_t)3 * DB * DB * 2);  // [3072,1024] concat q,k,v
    bf* woT   = alloc((size_t)DB * DB * 2);
    bf* cwqT  = alloc((size_t)DB * DA * 2);      // [1024,768]
    bf* ckvT  = alloc((size_t)2 * DB * DB * 2);  // [2048,1024] concat k,v
    bf* cwoT  = alloc((size_t)DB * DB * 2);
    bf* slA   = alloc((size_t)Mt * DB * 2);      // xbB -> xaB -> VcT
    bf* slQ   = alloc((size_t)Mt * DB * 2);      // Q   -> Xb
    bf* slK   = alloc((size_t)Mt * DB * 2);      // K   -> attn -> Qc
    bf* slV   = alloc((size_t)Mt * DB * 2);      // VT  -> Kc
    bf* S     = alloc((size_t)Bb * Nn * Nn * 2);

    const dim3 tb(32, 8);
    const dim3 blk(256);
    const dim3 blk5(512);
    const long sQ = (long)Nn * DB;
    const long sS = (long)Nn * Nn;
    const float* nf = nullptr;
    const bf*    nb = nullptr;
    bf*          no = nullptr;

    // ---- ingestion: weight transposes (f32 -> bf16), concat layouts ----
    transpose_f32_bf16<<<dim3(DB/32, DB/32), tb, 0, stream>>>(sa_wq, wqkvT,                 DB, DB);
    transpose_f32_bf16<<<dim3(DB/32, DB/32), tb, 0, stream>>>(sa_wk, wqkvT + (size_t)DB*DB, DB, DB);
    transpose_f32_bf16<<<dim3(DB/32, DB/32), tb, 0, stream>>>(sa_wv, wqkvT + (size_t)2*DB*DB, DB, DB);
    transpose_f32_bf16<<<dim3(DB/32, DB/32), tb, 0, stream>>>(sa_wo, woT,  DB, DB);
    transpose_f32_bf16<<<dim3(DB/32, DA/32), tb, 0, stream>>>(ca_wq, cwqT, DA, DB);
    transpose_f32_bf16<<<dim3(DB/32, DB/32), tb, 0, stream>>>(ca_wk, ckvT,                 DB, DB);
    transpose_f32_bf16<<<dim3(DB/32, DB/32), tb, 0, stream>>>(ca_wv, ckvT + (size_t)DB*DB, DB, DB);
    transpose_f32_bf16<<<dim3(DB/32, DB/32), tb, 0, stream>>>(ca_wo, cwoT, DB, DB);

    // ---- self-attention ----
    cast_f32_bf16<<<dim3((unsigned)(Mt * DB / 8 / 256)), blk, 0, stream>>>(x_b, slA, Mt * DB);
    // fused QKV: Q->slQ, K->slK, V->slV (transposed per batch)
    gemm256<<<dim3(3*DB/256, Mt/256, 1), blk5, 0, stream>>>(
        slA, wqkvT, sa_bq, sa_bk, sa_bv, nf, nb, slQ, slK, slV, nullptr,
        (int)Mt, 3*DB, DB, 1.0f, 0, 0, 0, 0b100, 3);
    // scores = (Q @ K^T) / 32
    gemm256<<<dim3(Nn/256, Nn/256, Bb), blk5, 0, stream>>>(
        slQ, slK, nf, nf, nf, nf, nb, S, no, no, nullptr,
        Nn, Nn, DB, 0.03125f, sQ, sQ, sS, 0, 1);
    softmax_rows<<<dim3((unsigned)(Bb * Nn)), blk, 0, stream>>>(S);
    // attn = P @ V (VT as B^T) -> slK (K dead)
    gemm256<<<dim3(DB/256, Nn/256, Bb), blk5, 0, stream>>>(
        S, slV, nf, nf, nf, nf, nb, slK, no, no, nullptr,
        Nn, DB, Nn, 1.0f, sS, sQ, sQ, 0, 1);
    // x_b_new = x_b(f32) + attn @ Wo + bo -> slQ (Q dead)
    gemm256<<<dim3(DB/256, Mt/256, 1), blk5, 0, stream>>>(
        slK, woT, sa_bo, nf, nf, x_b, nb, slQ, no, no, nullptr,
        (int)Mt, DB, DB, 1.0f, 0, 0, 0, 0, 1);

    // ---- cross-attention ----
    cast_f32_bf16<<<dim3((unsigned)(Mt * DA / 8 / 256)), blk, 0, stream>>>(x_a, slA, Mt * DA);
    // Qc = xa @ cwq -> slK (attn dead)   [K=768 -> 12 K-tiles, 6 iters]
    gemm256<<<dim3(DB/256, Mt/256, 1), blk5, 0, stream>>>(
        slA, cwqT, ca_bq, nf, nf, nf, nb, slK, no, no, nullptr,
        (int)Mt, DB, DA, 1.0f, 0, 0, 0, 0, 1);
    // fused cKV from Xb(slQ): Kc->slV (VT dead), Vc->slA transposed (xaB dead)
    gemm256<<<dim3(2*DB/256, Mt/256, 1), blk5, 0, stream>>>(
        slQ, ckvT, ca_bk, ca_bv, nf, nf, nb, slV, slA, no, nullptr,
        (int)Mt, 2*DB, DB, 1.0f, 0, 0, 0, 0b10, 2);
    // scores = (Qc @ Kc^T) / sqrt(768)
    gemm256<<<dim3(Nn/256, Nn/256, Bb), blk5, 0, stream>>>(
        slK, slV, nf, nf, nf, nf, nb, S, no, no, nullptr,
        Nn, Nn, DB, 0.036084391824351615f, sQ, sQ, sS, 0, 1);
    softmax_rows<<<dim3((unsigned)(Bb * Nn)), blk, 0, stream>>>(S);
    // ca_attn = P @ Vc -> slV (Kc dead)
    gemm256<<<dim3(DB/256, Nn/256, Bb), blk5, 0, stream>>>(
        S, slA, nf, nf, nf, nf, nb, slV, no, no, nullptr,
        Nn, DB, Nn, 1.0f, sS, sQ, sQ, 0, 1);
    // out(f32) = x_b_new(bf16, slQ) + ca_attn @ Wo + bo
    gemm256<<<dim3(DB/256, Mt/256, 1), blk5, 0, stream>>>(
        slV, cwoT, ca_bo, nf, nf, nf, slQ, no, no, no, out,
        (int)Mt, DB, DB, 1.0f, 0, 0, 0, 0, 1);
}